// Round 8
// baseline (1097.397 us; speedup 1.0000x reference)
//
#include <hip/hip_runtime.h>
#include <hip/hip_bf16.h>

#define B_TOK 2048
#define DDIM 1024
#define FDIM 4096
#define NE 16
#define NG 2
#define BD ((long)B_TOK * DDIM)

typedef unsigned short u16;
typedef __attribute__((ext_vector_type(8))) short bf16x8;   // 8 bf16 (4 VGPRs)
typedef __attribute__((ext_vector_type(4))) float f32x4;

// ---------- helpers ----------
__device__ inline u16 f2bf(float x) {           // RNE f32 -> bf16 bits
  union { float f; unsigned u; } v; v.f = x;
  return (u16)((v.u + 0x7fffu + ((v.u >> 16) & 1u)) >> 16);
}
__device__ inline float bfround(float x) {      // f32 -> bf16 -> f32 (matches astype(bf16))
  union { float f; unsigned u; } v; v.f = x;
  v.u = ((v.u + 0x7fffu + ((v.u >> 16) & 1u)) >> 16) << 16;
  return v.f;
}
// Abramowitz-Stegun 7.1.26 erf, |eps| <= 1.5e-7
__device__ inline float fast_erf(float x) {
  float ax = fabsf(x);
  float t = __builtin_amdgcn_rcpf(1.0f + 0.3275911f * ax);
  float poly = t * (0.254829592f + t * (-0.284496736f + t * (1.421413741f +
               t * (-1.453152027f + t * 1.061405429f))));
  float r = 1.0f - poly * __expf(-ax * ax);
  return copysignf(r, x);
}
__device__ inline float gelu_exact(float x) {
  return 0.5f * x * (1.0f + fast_erf(x * 0.70710678118654752440f));
}
__device__ inline void gload16(const void* g, void* l) {
  // LDS dest is wave-uniform base; HW adds lane*16 (guide m104/m108).
  __builtin_amdgcn_global_load_lds((const __attribute__((address_space(1))) void*)g,
                                   (__attribute__((address_space(3))) void*)l, 16, 0, 0);
}
__device__ inline float waveSum(float v) {
  v += __shfl_down(v, 32); v += __shfl_down(v, 16); v += __shfl_down(v, 8);
  v += __shfl_down(v, 4);  v += __shfl_down(v, 2);  v += __shfl_down(v, 1);
  return v;
}

// ---------- gating + loss partials ----------
__global__ __launch_bounds__(256) void gating_kernel(
    const float* __restrict__ logits, const int* __restrict__ masks,
    float* __restrict__ gates, float* __restrict__ loss)
{
  const int b = blockIdx.x * 256 + threadIdx.x;       // grid 8 x 256 == 2048
  const int lane = threadIdx.x & 63;
  const float* lr = logits + (long)b * NE;
  const int*   mr = masks  + (long)b * NE;
  float raw[NE]; int mk[NE];
  float mx = -1e30f;
#pragma unroll
  for (int e = 0; e < NE; ++e) { raw[e] = lr[e]; mx = fmaxf(mx, raw[e]); }
  float s = 0.f;
#pragma unroll
  for (int e = 0; e < NE; ++e) { raw[e] = expf(raw[e] - mx); s += raw[e]; }
  float inv = 1.0f / s;
#pragma unroll
  for (int e = 0; e < NE; ++e) raw[e] *= inv;
  float gs = 0.f;
#pragma unroll
  for (int e = 0; e < NE; ++e) { mk[e] = (mr[e] == 1); gs += mk[e] ? raw[e] : 0.f; }
  float ginv = 1.0f / (gs + 1e-9f);
  float* gr = gates + (long)b * NE;
#pragma unroll
  for (int e = 0; e < NE; ++e) gr[e] = (mk[e] ? raw[e] : 0.f) * ginv;
#pragma unroll
  for (int e = 0; e < NE; ++e) {
    float cs = waveSum(raw[e]);
    float cc = waveSum(mk[e] ? 1.f : 0.f);
    if (lane == 0) { atomicAdd(&loss[e], cs); atomicAdd(&loss[NE + e], cc); }
  }
  float t = waveSum(gs);
  if (lane == 0) atomicAdd(&loss[32], t);
}

__global__ void finalize_loss(const float* __restrict__ loss, float* __restrict__ out2) {
  if (threadIdx.x == 0) {
    float aug = 0.f;
    for (int e = 0; e < NE; ++e)
      aug += (loss[e] / (float)B_TOK) * (loss[NE + e] / (float)B_TOK);
    aug *= (1.0f / NE);
    float s = loss[32] / (float)B_TOK;
    out2[0] = aug;
    out2[1] = (1.f - s) * (1.f - s);
  }
}

// ---------- deterministic per-expert token compaction + inverse map ----------
__global__ __launch_bounds__(256) void compact_kernel(
    const int* __restrict__ masks, int* __restrict__ tok,
    int* __restrict__ pos, int* __restrict__ cnts)
{
  const int e = blockIdx.x, tid = threadIdx.x;
  const int lane = tid & 63, wave = tid >> 6;
  __shared__ int wcnt[4];
  __shared__ int runbase;
  if (tid == 0) runbase = 0;
  __syncthreads();
  for (int b0 = 0; b0 < B_TOK; b0 += 256) {
    int b = b0 + tid;
    int m = (masks[(long)b * NE + e] == 1);
    unsigned long long bal = __ballot(m);
    int pre = __popcll(bal & ((1ull << lane) - 1ull));
    if (lane == 0) wcnt[wave] = __popcll(bal);
    __syncthreads();
    int base = runbase;
    for (int w = 0; w < wave; ++w) base += wcnt[w];
    if (m) {
      int p = base + pre;
      tok[(e << 11) + p] = b;
      pos[(long)b * NE + e] = p;
    } else {
      pos[(long)b * NE + e] = -1;
    }
    __syncthreads();
    if (tid == 0) runbase += wcnt[0] + wcnt[1] + wcnt[2] + wcnt[3];
    __syncthreads();
  }
  const int cnt = runbase;
  const int cnt_pad = (cnt + 127) & ~127;
  for (int i = cnt + tid; i < cnt_pad; i += 256)
    tok[(e << 11) + i] = 0;          // safe row; pad output rows never read
  if (tid == 0) { cnts[e] = cnt; cnts[NE + e] = cnt_pad; }
}

// ---------- x f32 -> bf16 ----------
__global__ __launch_bounds__(256) void cvt_x_kernel(const float* __restrict__ x, u16* __restrict__ xb) {
  long i = ((long)blockIdx.x * 256 + threadIdx.x) * 4;
  float4 v = *(const float4*)&x[i];
  ushort4 o; o.x = f2bf(v.x); o.y = f2bf(v.y); o.z = f2bf(v.z); o.w = f2bf(v.w);
  *(ushort4*)&xb[i] = o;
}

// ---------- moe bias: moe_bias[b,d] = sum_e gates[b,e]*eb[e,d] ----------
__global__ __launch_bounds__(256) void bias_init_kernel(
    const float* __restrict__ gates, const float* __restrict__ eb,
    float* __restrict__ moe_bias)
{
  long i = (long)blockIdx.x * 256 + threadIdx.x;       // grid 8192 -> B*D
  int b = (int)(i >> 10), d = (int)(i & 1023);
  const float* gr = gates + (long)b * NE;
  float s = 0.f;
#pragma unroll
  for (int e = 0; e < NE; ++e) s += gr[e] * eb[e * DDIM + d];
  moe_bias[i] = s;
}

// ---------- transpose + f32->bf16: src [R,C] -> dst [C,R] ----------
__global__ __launch_bounds__(256) void transpose_cvt(
    const float* __restrict__ src, u16* __restrict__ dst,
    int R, int C, long sZ, long dZ)
{
  __shared__ float t[64][65];
  const float* s = src + (long)blockIdx.z * sZ;
  u16* d = dst + (long)blockIdx.z * dZ;
  const int c0 = blockIdx.x * 64, r0 = blockIdx.y * 64;
  const int tid = threadIdx.x;
#pragma unroll
  for (int it = 0; it < 4; ++it) {
    int idx = tid + it * 256;
    int r = idx >> 4, cq = (idx & 15) * 4;
    float4 v = *(const float4*)&s[(long)(r0 + r) * C + c0 + cq];
    t[r][cq] = v.x; t[r][cq + 1] = v.y; t[r][cq + 2] = v.z; t[r][cq + 3] = v.w;
  }
  __syncthreads();
#pragma unroll
  for (int it = 0; it < 4; ++it) {
    int idx = tid + it * 256;
    int c = idx >> 4, rq = (idx & 15) * 4;
    ushort4 o;
    o.x = f2bf(t[rq][c]); o.y = f2bf(t[rq+1][c]); o.z = f2bf(t[rq+2][c]); o.w = f2bf(t[rq+3][c]);
    *(ushort4*)&d[(long)(c0 + c) * R + r0 + rq] = o;
  }
}

// ---------- 128x128 bf16 MFMA GEMM, 3-buffer counted-vmcnt ring (r5-validated),
// + 2-bit LDS chunk swizzle (pre-swizzled global source, linear LDS dest, XOR'd
// reads — each 16-lane b128 cohort covers all 8 bank groups at 2 lanes = free).
// PROJ 0 (in-proj, K=1024): z<16 A rows gathered via tok (xb); z>=16 identity
//   (general). Epilogue: Hb[z] = bf16(gelu(acc)). Raster: by(M)-fastest.
// PROJ 1 (out-proj, K=4096): A = Hb[z]; epilogue: z<16 -> Eout[z], else
//   gen_p[z-16] (f32, pure writes). Raster: bx-fastest.
template<int PROJ>
__global__ __launch_bounds__(256) void gemm128s(
    const u16* __restrict__ A, int lda, long aZ,
    const u16* __restrict__ Bm, int ldb,
    u16* __restrict__ H,
    float* __restrict__ Eout, float* __restrict__ genp,
    const int* __restrict__ tok, const int* __restrict__ cnts)
{
  constexpr int KLEN = PROJ ? FDIM : DDIM;     // nt = 32 / 128; (nt-2)%3 == 0
  // raster + bijective chunked XCD swizzle (T divisible by 8 by construction)
  int lin;
  if (PROJ == 0)
    lin = ((int)blockIdx.z * gridDim.x + blockIdx.x) * gridDim.y + blockIdx.y;
  else
    lin = ((int)blockIdx.z * gridDim.y + blockIdx.y) * gridDim.x + blockIdx.x;
  const int T = gridDim.x * gridDim.y * gridDim.z;
  lin = (lin & 7) * (T >> 3) + (lin >> 3);
  int bx, by, z;
  if (PROJ == 0) { by = lin % gridDim.y; int r2 = lin / gridDim.y; bx = r2 % gridDim.x; z = r2 / gridDim.x; }
  else           { bx = lin % gridDim.x; int r2 = lin / gridDim.x; by = r2 % gridDim.y; z = r2 / gridDim.y; }

  const int m0 = by * 128, n0 = bx * 128;
  if (z < NE && m0 >= cnts[NE + z]) return;    // routed: beyond padded count

  __shared__ u16 sA[3][128 * 32];
  __shared__ u16 sB[3][128 * 32];
  const u16* Az = (PROJ == 0) ? A : A + (long)z * aZ;
  const u16* Bz = Bm + (long)z * ((long)DDIM * FDIM);
  const int tid = threadIdx.x, lane = tid & 63, wave = tid >> 6;

  // staging: linear LDS, 2 passes of 16B/thread per operand; source k pre-swizzled
  const int off = tid * 16;            // byte offset in 8KB tile (pass 0)
  const int sr  = off >> 6;            // row 0..63 (64B per row of 32 bf16)
  const int ske = ((off & 63) >> 1) ^ (((sr >> 1) & 3) << 3);   // swizzled src k-elem
  int arow0 = m0 + sr, arow1 = m0 + sr + 64;
  if (PROJ == 0 && z < NE) {           // gather source rows (per-lane global ok)
    const int* tz = tok + (z << 11);
    arow0 = tz[arow0]; arow1 = tz[arow1];
  }
  const u16* gA0 = Az + (long)arow0 * lda + ske;
  const u16* gA1 = Az + (long)arow1 * lda + ske;
  const u16* gB0 = Bz + (long)(n0 + sr) * ldb + ske;
  const u16* gB1 = Bz + (long)(n0 + sr + 64) * ldb + ske;

  const int wr = wave >> 1, wc = wave & 1;            // 2x2 waves of 64x64
  const int fr = lane & 15;
  const int fks = ((lane >> 4) * 8) ^ (((fr >> 1) & 3) << 3);   // swizzled read k-elem
  const int rAo = (wr * 64 + fr) * 32 + fks;
  const int rBo = (wc * 64 + fr) * 32 + fks;

  f32x4 zero = {0.f, 0.f, 0.f, 0.f};
  f32x4 acc[4][4];
#pragma unroll
  for (int m = 0; m < 4; ++m)
#pragma unroll
    for (int n = 0; n < 4; ++n) acc[m][n] = zero;

  auto STAGE = [&](u16* dA, u16* dB, int t) {
    const int kk = t << 5;
    gload16(gA0 + kk, dA + wave * 512);
    gload16(gA1 + kk, dA + 2048 + wave * 512);
    gload16(gB0 + kk, dB + wave * 512);
    gload16(gB1 + kk, dB + 2048 + wave * 512);
  };
  auto COMPUTE = [&](const u16* bA, const u16* bB) {
    bf16x8 av[4], bv[4];
#pragma unroll
    for (int m = 0; m < 4; ++m) av[m] = *(const bf16x8*)(bA + rAo + m * 512);
#pragma unroll
    for (int n = 0; n < 4; ++n) bv[n] = *(const bf16x8*)(bB + rBo + n * 512);
#pragma unroll
    for (int m = 0; m < 4; ++m)
#pragma unroll
      for (int n = 0; n < 4; ++n)
        acc[m][n] = __builtin_amdgcn_mfma_f32_16x16x32_bf16(av[m], bv[n], acc[m][n], 0, 0, 0);
  };

  // r5-validated pipeline: stage K-step (t+2), counted vmcnt(8) keeps two tiles
  // in flight (never 0 in steady state), barrier, compute K-step t.
#define PIPE(SA, SB, KIDX, CA, CB)                                   \
  STAGE(SA, SB, KIDX);                                               \
  asm volatile("s_waitcnt vmcnt(8)" ::: "memory");                   \
  __builtin_amdgcn_s_barrier();                                      \
  asm volatile("" ::: "memory");                                     \
  COMPUTE(CA, CB);                                                   \
  asm volatile("" ::: "memory");                                     \
  __builtin_amdgcn_s_barrier();                                      \
  asm volatile("" ::: "memory");

  const int nt = KLEN >> 5;            // (nt-2) % 3 == 0 by construction
  STAGE(sA[0], sB[0], 0);
  STAGE(sA[1], sB[1], 1);
  for (int t = 0; t + 2 < nt; t += 3) {
    PIPE(sA[2], sB[2], t + 2, sA[0], sB[0]);
    PIPE(sA[0], sB[0], t + 3, sA[1], sB[1]);
    PIPE(sA[1], sB[1], t + 4, sA[2], sB[2]);
  }
  asm volatile("s_waitcnt vmcnt(4)" ::: "memory");
  __builtin_amdgcn_s_barrier();
  asm volatile("" ::: "memory");
  COMPUTE(sA[0], sB[0]);               // K-step nt-2
  asm volatile("s_waitcnt vmcnt(0)" ::: "memory");
  __builtin_amdgcn_s_barrier();
  asm volatile("" ::: "memory");
  COMPUTE(sA[1], sB[1]);               // K-step nt-1
#undef PIPE

  // epilogue: C/D map col=lane&15, row=(lane>>4)*4+j  (guide m89/m91)
  const int er = m0 + wr * 64 + (lane >> 4) * 4;
  const int ec = n0 + wc * 64 + fr;
  if (PROJ == 0) {
    u16* Hz = H + (long)z * ((long)B_TOK * FDIM);
#pragma unroll
    for (int m = 0; m < 4; ++m)
#pragma unroll
      for (int n = 0; n < 4; ++n) {
        f32x4 v = acc[m][n];
        int rb = er + m * 16, cb = ec + n * 16;
#pragma unroll
        for (int j = 0; j < 4; ++j)
          Hz[(long)(rb + j) * FDIM + cb] = f2bf(gelu_exact(v[j]));
      }
  } else {
    float* Cz = (z < NE) ? (Eout + (long)z * BD) : (genp + (long)(z - NE) * BD);
#pragma unroll
    for (int m = 0; m < 4; ++m)
#pragma unroll
      for (int n = 0; n < 4; ++n) {
        f32x4 v = acc[m][n];
        int rb = er + m * 16, cb = ec + n * 16;
#pragma unroll
        for (int j = 0; j < 4; ++j)
          Cz[(long)(rb + j) * DDIM + cb] = v[j];
      }
  }
}

// ---------- combine (gate-weighted gather) + general + residual + LayerNorm ----------
__global__ __launch_bounds__(256) void combine_ln_kernel(
    const float* __restrict__ x, const float* __restrict__ moe_bias,
    const float* __restrict__ Eout, const float* __restrict__ gen_p,
    const float* __restrict__ gb,
    const int* __restrict__ pos, const float* __restrict__ gates,
    const float* __restrict__ gamma, const float* __restrict__ beta,
    float* __restrict__ out)
{
  const int b = blockIdx.x, tid = threadIdx.x;
  const int lane = tid & 63, wave = tid >> 6;
  const long base = (long)b * DDIM;
  __shared__ int posr[NE];
  __shared__ float gr[NE];
  __shared__ float red[4];
  if (tid < NE) { posr[tid] = pos[(long)b * NE + tid]; gr[tid] = gates[(long)b * NE + tid]; }
  __syncthreads();
  float y[4];
  float ls = 0.f;
#pragma unroll
  for (int i = 0; i < 4; ++i) {
    int d = tid + i * 256;
    long idx = base + d;
    float moe = moe_bias[idx];
#pragma unroll
    for (int e = 0; e < NE; ++e) {
      int p = posr[e];                                  // block-uniform -> no divergence
      if (p >= 0) moe += gr[e] * Eout[((long)e * B_TOK + p) * DDIM + d];
    }
    moe = bfround(moe);                                 // matches ref's bf16 cast of moe_out
    float ge = gb[d] + gb[DDIM + d] + gen_p[idx] + gen_p[BD + idx];
    y[i] = moe + ge + x[idx];
    ls += y[i];
  }
  float t = waveSum(ls);
  if (lane == 0) red[wave] = t;
  __syncthreads();
  float mean = (red[0] + red[1] + red[2] + red[3]) * (1.0f / DDIM);
  __syncthreads();
  float vs = 0.f;
#pragma unroll
  for (int i = 0; i < 4; ++i) { float d2 = y[i] - mean; vs += d2 * d2; }
  t = waveSum(vs);
  if (lane == 0) red[wave] = t;
  __syncthreads();
  float var = (red[0] + red[1] + red[2] + red[3]) * (1.0f / DDIM);
  float inv = rsqrtf(var + 1e-5f);
#pragma unroll
  for (int i = 0; i < 4; ++i) {
    int d = tid + i * 256;
    out[base + d] = (y[i] - mean) * inv * gamma[d] + beta[d];
  }
}

// ---------- orchestration ----------
extern "C" void kernel_launch(void* const* d_in, const int* in_sizes, int n_in,
                              void* d_out, int out_size, void* d_ws, size_t ws_size,
                              hipStream_t stream)
{
  const float* x      = (const float*)d_in[0];
  const float* logits = (const float*)d_in[1];
  const int*   masks  = (const int*)d_in[2];
  const float* ew_in  = (const float*)d_in[3];
  const float* ew_out = (const float*)d_in[4];
  const float* eb_out = (const float*)d_in[5];
  const float* gw_in  = (const float*)d_in[6];
  const float* gw_out = (const float*)d_in[7];
  const float* gb_out = (const float*)d_in[8];
  const float* gamma  = (const float*)d_in[9];
  const float* beta   = (const float*)d_in[10];
  float* out = (float*)d_out;

  char* w = (char*)d_ws;
  size_t off = 0;
  auto alloc = [&](size_t bytes) -> void* {
    off = (off + 4095) & ~(size_t)4095;
    void* p = w + off; off += bytes; return p;
  };
  const long DF = (long)DDIM * FDIM;          // 4.19M elems
  const long BF = (long)B_TOK * FDIM;         // 8.39M elems
  const int  NZ = NE + NG;                    // 18 unified expert slots

  float* gates    = (float*)alloc((size_t)B_TOK * NE * 4);
  float* loss     = (float*)alloc(64 * 4);
  int*   tok      = (int*)alloc((size_t)NE * B_TOK * 4);
  int*   pos      = (int*)alloc((size_t)B_TOK * NE * 4);
  int*   cnts     = (int*)alloc(2 * NE * 4);
  u16*   xb       = (u16*)alloc((size_t)BD * 2);
  float* moe_bias = (float*)alloc((size_t)BD * 4);
  float* gen_p    = (float*)alloc((size_t)NG * BD * 4);          // 2 slices (per g)
  float* Eout     = (float*)alloc((size_t)NE * BD * 4);          // per-expert compact f32
  u16*   WinT     = (u16*)alloc((size_t)NZ * DF * 2);            // [F,D] per slot
  u16*   WoutT    = (u16*)alloc((size_t)NZ * DF * 2);            // [D,F] per slot
  u16*   Hb       = (u16*)alloc((size_t)NZ * BF * 2);            // gelu acts per slot

  hipMemsetAsync(loss, 0, 64 * 4, stream);
  gating_kernel<<<8, 256, 0, stream>>>(logits, masks, gates, loss);
  finalize_loss<<<1, 64, 0, stream>>>(loss, out + BD);
  compact_kernel<<<NE, 256, 0, stream>>>(masks, tok, pos, cnts);
  cvt_x_kernel<<<2048, 256, 0, stream>>>(x, xb);
  bias_init_kernel<<<8192, 256, 0, stream>>>(gates, eb_out, moe_bias);

  // all weight transposes up front (routed slots 0..15, general 16..17)
  transpose_cvt<<<dim3(FDIM/64, DDIM/64, NE), 256, 0, stream>>>(
      ew_in, WinT, DDIM, FDIM, DF, DF);
  transpose_cvt<<<dim3(FDIM/64, DDIM/64, NG), 256, 0, stream>>>(
      gw_in, WinT + (long)NE * DF, DDIM, FDIM, DF, DF);
  transpose_cvt<<<dim3(DDIM/64, FDIM/64, NE), 256, 0, stream>>>(
      ew_out, WoutT, FDIM, DDIM, DF, DF);
  transpose_cvt<<<dim3(DDIM/64, FDIM/64, NG), 256, 0, stream>>>(
      gw_out, WoutT + (long)NE * DF, FDIM, DDIM, DF, DF);

  // in-proj, all 18 slots: [M,1024] x [4096,1024]^T -> Hb (bf16 gelu)
  gemm128s<0><<<dim3(FDIM/128, B_TOK/128, NZ), 256, 0, stream>>>(
      xb, DDIM, 0L, WinT, DDIM,
      Hb, nullptr, nullptr, tok, cnts);
  // out-proj, all 18 slots: [M,4096] x [1024,4096]^T -> Eout / gen_p (f32)
  gemm128s<1><<<dim3(DDIM/128, B_TOK/128, NZ), 256, 0, stream>>>(
      Hb, FDIM, BF, WoutT, FDIM,
      nullptr, Eout, gen_p, nullptr, cnts);

  combine_ln_kernel<<<B_TOK, 256, 0, stream>>>(
      x, moe_bias, Eout, gen_p, gb_out, pos, gates, gamma, beta, out);
}

// Round 9
// 1017.736 us; speedup vs baseline: 1.0783x; 1.0783x over previous
//
#include <hip/hip_runtime.h>
#include <hip/hip_bf16.h>

#define B_TOK 2048
#define DDIM 1024
#define FDIM 4096
#define NE 16
#define NG 2
#define BD ((long)B_TOK * DDIM)

typedef unsigned short u16;
typedef __attribute__((ext_vector_type(8))) short bf16x8;   // 8 bf16 (4 VGPRs)
typedef __attribute__((ext_vector_type(4))) float f32x4;

// ---------- helpers ----------
__device__ inline u16 f2bf(float x) {           // RNE f32 -> bf16 bits
  union { float f; unsigned u; } v; v.f = x;
  return (u16)((v.u + 0x7fffu + ((v.u >> 16) & 1u)) >> 16);
}
__device__ inline float bfround(float x) {      // f32 -> bf16 -> f32 (matches astype(bf16))
  union { float f; unsigned u; } v; v.f = x;
  v.u = ((v.u + 0x7fffu + ((v.u >> 16) & 1u)) >> 16) << 16;
  return v.f;
}
// Abramowitz-Stegun 7.1.26 erf, |eps| <= 1.5e-7
__device__ inline float fast_erf(float x) {
  float ax = fabsf(x);
  float t = __builtin_amdgcn_rcpf(1.0f + 0.3275911f * ax);
  float poly = t * (0.254829592f + t * (-0.284496736f + t * (1.421413741f +
               t * (-1.453152027f + t * 1.061405429f))));
  float r = 1.0f - poly * __expf(-ax * ax);
  return copysignf(r, x);
}
__device__ inline float gelu_exact(float x) {
  return 0.5f * x * (1.0f + fast_erf(x * 0.70710678118654752440f));
}
__device__ inline void gload16(const void* g, void* l) {
  // LDS dest is wave-uniform base; HW adds lane*16 (guide m104/m108).
  __builtin_amdgcn_global_load_lds((const __attribute__((address_space(1))) void*)g,
                                   (__attribute__((address_space(3))) void*)l, 16, 0, 0);
}
__device__ inline float waveSum(float v) {
  v += __shfl_down(v, 32); v += __shfl_down(v, 16); v += __shfl_down(v, 8);
  v += __shfl_down(v, 4);  v += __shfl_down(v, 2);  v += __shfl_down(v, 1);
  return v;
}

// ---------- gating + loss partials ----------
__global__ __launch_bounds__(256) void gating_kernel(
    const float* __restrict__ logits, const int* __restrict__ masks,
    float* __restrict__ gates, float* __restrict__ loss)
{
  const int b = blockIdx.x * 256 + threadIdx.x;       // grid 8 x 256 == 2048
  const int lane = threadIdx.x & 63;
  const float* lr = logits + (long)b * NE;
  const int*   mr = masks  + (long)b * NE;
  float raw[NE]; int mk[NE];
  float mx = -1e30f;
#pragma unroll
  for (int e = 0; e < NE; ++e) { raw[e] = lr[e]; mx = fmaxf(mx, raw[e]); }
  float s = 0.f;
#pragma unroll
  for (int e = 0; e < NE; ++e) { raw[e] = expf(raw[e] - mx); s += raw[e]; }
  float inv = 1.0f / s;
#pragma unroll
  for (int e = 0; e < NE; ++e) raw[e] *= inv;
  float gs = 0.f;
#pragma unroll
  for (int e = 0; e < NE; ++e) { mk[e] = (mr[e] == 1); gs += mk[e] ? raw[e] : 0.f; }
  float ginv = 1.0f / (gs + 1e-9f);
  float* gr = gates + (long)b * NE;
#pragma unroll
  for (int e = 0; e < NE; ++e) gr[e] = (mk[e] ? raw[e] : 0.f) * ginv;
#pragma unroll
  for (int e = 0; e < NE; ++e) {
    float cs = waveSum(raw[e]);
    float cc = waveSum(mk[e] ? 1.f : 0.f);
    if (lane == 0) { atomicAdd(&loss[e], cs); atomicAdd(&loss[NE + e], cc); }
  }
  float t = waveSum(gs);
  if (lane == 0) atomicAdd(&loss[32], t);
}

__global__ void finalize_loss(const float* __restrict__ loss, float* __restrict__ out2) {
  if (threadIdx.x == 0) {
    float aug = 0.f;
    for (int e = 0; e < NE; ++e)
      aug += (loss[e] / (float)B_TOK) * (loss[NE + e] / (float)B_TOK);
    aug *= (1.0f / NE);
    float s = loss[32] / (float)B_TOK;
    out2[0] = aug;
    out2[1] = (1.f - s) * (1.f - s);
  }
}

// ---------- deterministic per-expert token compaction + inverse map ----------
__global__ __launch_bounds__(256) void compact_kernel(
    const int* __restrict__ masks, int* __restrict__ tok,
    int* __restrict__ pos, int* __restrict__ cnts)
{
  const int e = blockIdx.x, tid = threadIdx.x;
  const int lane = tid & 63, wave = tid >> 6;
  __shared__ int wcnt[4];
  __shared__ int runbase;
  if (tid == 0) runbase = 0;
  __syncthreads();
  for (int b0 = 0; b0 < B_TOK; b0 += 256) {
    int b = b0 + tid;
    int m = (masks[(long)b * NE + e] == 1);
    unsigned long long bal = __ballot(m);
    int pre = __popcll(bal & ((1ull << lane) - 1ull));
    if (lane == 0) wcnt[wave] = __popcll(bal);
    __syncthreads();
    int base = runbase;
    for (int w = 0; w < wave; ++w) base += wcnt[w];
    if (m) {
      int p = base + pre;
      tok[(e << 11) + p] = b;
      pos[(long)b * NE + e] = p;
    } else {
      pos[(long)b * NE + e] = -1;
    }
    __syncthreads();
    if (tid == 0) runbase += wcnt[0] + wcnt[1] + wcnt[2] + wcnt[3];
    __syncthreads();
  }
  const int cnt = runbase;
  const int cnt_pad = (cnt + 127) & ~127;
  for (int i = cnt + tid; i < cnt_pad; i += 256)
    tok[(e << 11) + i] = 0;          // safe row; pad output rows never read
  if (tid == 0) { cnts[e] = cnt; cnts[NE + e] = cnt_pad; }
}

// ---------- x f32 -> bf16 ----------
__global__ __launch_bounds__(256) void cvt_x_kernel(const float* __restrict__ x, u16* __restrict__ xb) {
  long i = ((long)blockIdx.x * 256 + threadIdx.x) * 4;
  float4 v = *(const float4*)&x[i];
  ushort4 o; o.x = f2bf(v.x); o.y = f2bf(v.y); o.z = f2bf(v.z); o.w = f2bf(v.w);
  *(ushort4*)&xb[i] = o;
}

// ---------- moe bias: moe_bias[b,d] = sum_e gates[b,e]*eb[e,d] ----------
__global__ __launch_bounds__(256) void bias_init_kernel(
    const float* __restrict__ gates, const float* __restrict__ eb,
    float* __restrict__ moe_bias)
{
  long i = (long)blockIdx.x * 256 + threadIdx.x;       // grid 8192 -> B*D
  int b = (int)(i >> 10), d = (int)(i & 1023);
  const float* gr = gates + (long)b * NE;
  float s = 0.f;
#pragma unroll
  for (int e = 0; e < NE; ++e) s += gr[e] * eb[e * DDIM + d];
  moe_bias[i] = s;
}

// ---------- transpose + f32->bf16: src [R,C] -> dst [C,R] ----------
__global__ __launch_bounds__(256) void transpose_cvt(
    const float* __restrict__ src, u16* __restrict__ dst,
    int R, int C, long sZ, long dZ)
{
  __shared__ float t[64][65];
  const float* s = src + (long)blockIdx.z * sZ;
  u16* d = dst + (long)blockIdx.z * dZ;
  const int c0 = blockIdx.x * 64, r0 = blockIdx.y * 64;
  const int tid = threadIdx.x;
#pragma unroll
  for (int it = 0; it < 4; ++it) {
    int idx = tid + it * 256;
    int r = idx >> 4, cq = (idx & 15) * 4;
    float4 v = *(const float4*)&s[(long)(r0 + r) * C + c0 + cq];
    t[r][cq] = v.x; t[r][cq + 1] = v.y; t[r][cq + 2] = v.z; t[r][cq + 3] = v.w;
  }
  __syncthreads();
#pragma unroll
  for (int it = 0; it < 4; ++it) {
    int idx = tid + it * 256;
    int c = idx >> 4, rq = (idx & 15) * 4;
    ushort4 o;
    o.x = f2bf(t[rq][c]); o.y = f2bf(t[rq+1][c]); o.z = f2bf(t[rq+2][c]); o.w = f2bf(t[rq+3][c]);
    *(ushort4*)&d[(long)(c0 + c) * R + r0 + rq] = o;
  }
}

// ---------- 128x128 bf16 MFMA GEMM — r5-validated 3-buffer counted-vmcnt ring.
// PROJ 0 (in-proj, K=1024): z<16 A rows gathered via tok (xb); z>=16 identity
//   (general experts). Epilogue: Hb[z] = bf16(gelu(acc)).
// PROJ 1 (out-proj, K=4096): A = Hb[z] compact rows; epilogue: z<16 -> Eout[z],
//   z>=16 -> gen_p[z-16] (f32, pure writes; no pre-zero needed).
// Raster/addressing identical to the r5 kernel (bx-fastest lin + bijective XCD
// chunk swizzle; linear LDS, no swizzle).
template<int PROJ>
__global__ __launch_bounds__(256) void gemm128r(
    const u16* __restrict__ A, int lda, long aZ,
    const u16* __restrict__ Bm, int ldb,
    u16* __restrict__ H,
    float* __restrict__ Eout, float* __restrict__ genp,
    const int* __restrict__ tok, const int* __restrict__ cnts)
{
  constexpr int KLEN = PROJ ? FDIM : DDIM;     // nt = 128 / 32; (nt-2)%3 == 0
  // bijective chunked XCD swizzle (T divisible by 8 by construction)
  int lin = ((int)blockIdx.z * gridDim.y + blockIdx.y) * gridDim.x + blockIdx.x;
  const int T = gridDim.x * gridDim.y * gridDim.z;
  lin = (lin & 7) * (T >> 3) + (lin >> 3);
  const int bx = lin % gridDim.x;
  const int rest = lin / gridDim.x;
  const int by = rest % gridDim.y;
  const int z  = rest / gridDim.y;

  const int m0 = by * 128, n0 = bx * 128;
  if (z < NE && m0 >= cnts[NE + z]) return;    // routed: beyond padded count

  __shared__ u16 sA[3][128 * 32];
  __shared__ u16 sB[3][128 * 32];
  const u16* Az = (PROJ == 0) ? A : A + (long)z * aZ;
  const u16* Bz = Bm + (long)z * ((long)DDIM * FDIM);
  const int tid = threadIdx.x, lane = tid & 63, wave = tid >> 6;

  // staging: linear LDS, 2 passes of 16B/thread per operand
  const int off = tid * 16;            // byte offset in 8KB tile (pass 0)
  const int sr  = off >> 6;            // row 0..63 (64B per row of 32 bf16)
  const int ske = (off & 63) >> 1;     // k element offset within row
  int arow0 = m0 + sr, arow1 = m0 + sr + 64;
  if (PROJ == 0 && z < NE) {           // gather source rows (per-lane global ok)
    const int* tz = tok + (z << 11);
    arow0 = tz[arow0]; arow1 = tz[arow1];
  }
  const u16* gA0 = Az + (long)arow0 * lda + ske;
  const u16* gA1 = Az + (long)arow1 * lda + ske;
  const u16* gB0 = Bz + (long)(n0 + sr) * ldb + ske;
  const u16* gB1 = Bz + (long)(n0 + sr + 64) * ldb + ske;

  const int wr = wave >> 1, wc = wave & 1;            // 2x2 waves of 64x64
  const int fr = lane & 15, fk = (lane >> 4) * 8;
  const int rAo = (wr * 64 + fr) * 32 + fk;
  const int rBo = (wc * 64 + fr) * 32 + fk;

  f32x4 zero = {0.f, 0.f, 0.f, 0.f};
  f32x4 acc[4][4];
#pragma unroll
  for (int m = 0; m < 4; ++m)
#pragma unroll
    for (int n = 0; n < 4; ++n) acc[m][n] = zero;

  auto STAGE = [&](u16* dA, u16* dB, int t) {
    const int kk = t << 5;
    gload16(gA0 + kk, dA + wave * 512);
    gload16(gA1 + kk, dA + 2048 + wave * 512);
    gload16(gB0 + kk, dB + wave * 512);
    gload16(gB1 + kk, dB + 2048 + wave * 512);
  };
  auto COMPUTE = [&](const u16* bA, const u16* bB) {
    bf16x8 av[4], bv[4];
#pragma unroll
    for (int m = 0; m < 4; ++m) av[m] = *(const bf16x8*)(bA + rAo + m * 512);
#pragma unroll
    for (int n = 0; n < 4; ++n) bv[n] = *(const bf16x8*)(bB + rBo + n * 512);
#pragma unroll
    for (int m = 0; m < 4; ++m)
#pragma unroll
      for (int n = 0; n < 4; ++n)
        acc[m][n] = __builtin_amdgcn_mfma_f32_16x16x32_bf16(av[m], bv[n], acc[m][n], 0, 0, 0);
  };

  // r5-validated pipeline: stage K-step (t+2), counted vmcnt(8) keeps two tiles
  // in flight (never 0 in steady state), barrier, compute K-step t.
#define PIPE(SA, SB, KIDX, CA, CB)                                   \
  STAGE(SA, SB, KIDX);                                               \
  asm volatile("s_waitcnt vmcnt(8)" ::: "memory");                   \
  __builtin_amdgcn_s_barrier();                                      \
  asm volatile("" ::: "memory");                                     \
  COMPUTE(CA, CB);                                                   \
  asm volatile("" ::: "memory");                                     \
  __builtin_amdgcn_s_barrier();                                      \
  asm volatile("" ::: "memory");

  const int nt = KLEN >> 5;            // (nt-2) % 3 == 0 by construction
  STAGE(sA[0], sB[0], 0);
  STAGE(sA[1], sB[1], 1);
  for (int t = 0; t + 2 < nt; t += 3) {
    PIPE(sA[2], sB[2], t + 2, sA[0], sB[0]);
    PIPE(sA[0], sB[0], t + 3, sA[1], sB[1]);
    PIPE(sA[1], sB[1], t + 4, sA[2], sB[2]);
  }
  asm volatile("s_waitcnt vmcnt(4)" ::: "memory");
  __builtin_amdgcn_s_barrier();
  asm volatile("" ::: "memory");
  COMPUTE(sA[0], sB[0]);               // K-step nt-2
  asm volatile("s_waitcnt vmcnt(0)" ::: "memory");
  __builtin_amdgcn_s_barrier();
  asm volatile("" ::: "memory");
  COMPUTE(sA[1], sB[1]);               // K-step nt-1
#undef PIPE

  // epilogue: C/D map col=lane&15, row=(lane>>4)*4+j  (guide m89/m91)
  const int er = m0 + wr * 64 + (lane >> 4) * 4;
  const int ec = n0 + wc * 64 + fr;
  if (PROJ == 0) {
    u16* Hz = H + (long)z * ((long)B_TOK * FDIM);
#pragma unroll
    for (int m = 0; m < 4; ++m)
#pragma unroll
      for (int n = 0; n < 4; ++n) {
        f32x4 v = acc[m][n];
        int rb = er + m * 16, cb = ec + n * 16;
#pragma unroll
        for (int j = 0; j < 4; ++j)
          Hz[(long)(rb + j) * FDIM + cb] = f2bf(gelu_exact(v[j]));
      }
  } else {
    float* Cz = (z < NE) ? (Eout + (long)z * BD) : (genp + (long)(z - NE) * BD);
#pragma unroll
    for (int m = 0; m < 4; ++m)
#pragma unroll
      for (int n = 0; n < 4; ++n) {
        f32x4 v = acc[m][n];
        int rb = er + m * 16, cb = ec + n * 16;
#pragma unroll
        for (int j = 0; j < 4; ++j)
          Cz[(long)(rb + j) * DDIM + cb] = v[j];
      }
  }
}

// ---------- combine (gate-weighted gather) + general + residual + LayerNorm ----------
__global__ __launch_bounds__(256) void combine_ln_kernel(
    const float* __restrict__ x, const float* __restrict__ moe_bias,
    const float* __restrict__ Eout, const float* __restrict__ gen_p,
    const float* __restrict__ gb,
    const int* __restrict__ pos, const float* __restrict__ gates,
    const float* __restrict__ gamma, const float* __restrict__ beta,
    float* __restrict__ out)
{
  const int b = blockIdx.x, tid = threadIdx.x;
  const int lane = tid & 63, wave = tid >> 6;
  const long base = (long)b * DDIM;
  __shared__ int posr[NE];
  __shared__ float gr[NE];
  __shared__ float red[4];
  if (tid < NE) { posr[tid] = pos[(long)b * NE + tid]; gr[tid] = gates[(long)b * NE + tid]; }
  __syncthreads();
  float y[4];
  float ls = 0.f;
#pragma unroll
  for (int i = 0; i < 4; ++i) {
    int d = tid + i * 256;
    long idx = base + d;
    float moe = moe_bias[idx];
#pragma unroll
    for (int e = 0; e < NE; ++e) {
      int p = posr[e];                                  // block-uniform -> no divergence
      if (p >= 0) moe += gr[e] * Eout[((long)e * B_TOK + p) * DDIM + d];
    }
    moe = bfround(moe);                                 // matches ref's bf16 cast of moe_out
    float ge = gb[d] + gb[DDIM + d] + gen_p[idx] + gen_p[BD + idx];
    y[i] = moe + ge + x[idx];
    ls += y[i];
  }
  float t = waveSum(ls);
  if (lane == 0) red[wave] = t;
  __syncthreads();
  float mean = (red[0] + red[1] + red[2] + red[3]) * (1.0f / DDIM);
  __syncthreads();
  float vs = 0.f;
#pragma unroll
  for (int i = 0; i < 4; ++i) { float d2 = y[i] - mean; vs += d2 * d2; }
  t = waveSum(vs);
  if (lane == 0) red[wave] = t;
  __syncthreads();
  float var = (red[0] + red[1] + red[2] + red[3]) * (1.0f / DDIM);
  float inv = rsqrtf(var + 1e-5f);
#pragma unroll
  for (int i = 0; i < 4; ++i) {
    int d = tid + i * 256;
    out[base + d] = (y[i] - mean) * inv * gamma[d] + beta[d];
  }
}

// ---------- orchestration ----------
extern "C" void kernel_launch(void* const* d_in, const int* in_sizes, int n_in,
                              void* d_out, int out_size, void* d_ws, size_t ws_size,
                              hipStream_t stream)
{
  const float* x      = (const float*)d_in[0];
  const float* logits = (const float*)d_in[1];
  const int*   masks  = (const int*)d_in[2];
  const float* ew_in  = (const float*)d_in[3];
  const float* ew_out = (const float*)d_in[4];
  const float* eb_out = (const float*)d_in[5];
  const float* gw_in  = (const float*)d_in[6];
  const float* gw_out = (const float*)d_in[7];
  const float* gb_out = (const float*)d_in[8];
  const float* gamma  = (const float*)d_in[9];
  const float* beta   = (const float*)d_in[10];
  float* out = (float*)d_out;

  char* w = (char*)d_ws;
  size_t off = 0;
  auto alloc = [&](size_t bytes) -> void* {
    off = (off + 4095) & ~(size_t)4095;
    void* p = w + off; off += bytes; return p;
  };
  const long DF = (long)DDIM * FDIM;          // 4.19M elems
  const long BF = (long)B_TOK * FDIM;         // 8.39M elems
  const int  NZ = NE + NG;                    // 18 unified expert slots

  float* gates    = (float*)alloc((size_t)B_TOK * NE * 4);
  float* loss     = (float*)alloc(64 * 4);
  int*   tok      = (int*)alloc((size_t)NE * B_TOK * 4);
  int*   pos      = (int*)alloc((size_t)B_TOK * NE * 4);
  int*   cnts     = (int*)alloc(2 * NE * 4);
  u16*   xb       = (u16*)alloc((size_t)BD * 2);
  float* moe_bias = (float*)alloc((size_t)BD * 4);
  float* gen_p    = (float*)alloc((size_t)NG * BD * 4);          // 2 slices (per g)
  float* Eout     = (float*)alloc((size_t)NE * BD * 4);          // per-expert compact f32
  u16*   WinT     = (u16*)alloc((size_t)NZ * DF * 2);            // [F,D] per slot
  u16*   WoutT    = (u16*)alloc((size_t)NZ * DF * 2);            // [D,F] per slot
  u16*   Hb       = (u16*)alloc((size_t)NZ * BF * 2);            // gelu acts per slot

  hipMemsetAsync(loss, 0, 64 * 4, stream);
  gating_kernel<<<8, 256, 0, stream>>>(logits, masks, gates, loss);
  finalize_loss<<<1, 64, 0, stream>>>(loss, out + BD);
  compact_kernel<<<NE, 256, 0, stream>>>(masks, tok, pos, cnts);
  cvt_x_kernel<<<2048, 256, 0, stream>>>(x, xb);
  bias_init_kernel<<<8192, 256, 0, stream>>>(gates, eb_out, moe_bias);

  // all weight transposes up front (routed slots 0..15, general 16..17)
  transpose_cvt<<<dim3(FDIM/64, DDIM/64, NE), 256, 0, stream>>>(
      ew_in, WinT, DDIM, FDIM, DF, DF);
  transpose_cvt<<<dim3(FDIM/64, DDIM/64, NG), 256, 0, stream>>>(
      gw_in, WinT + (long)NE * DF, DDIM, FDIM, DF, DF);
  transpose_cvt<<<dim3(DDIM/64, FDIM/64, NE), 256, 0, stream>>>(
      ew_out, WoutT, FDIM, DDIM, DF, DF);
  transpose_cvt<<<dim3(DDIM/64, FDIM/64, NG), 256, 0, stream>>>(
      gw_out, WoutT + (long)NE * DF, FDIM, DDIM, DF, DF);

  // in-proj, all 18 slots: [M,1024] x [4096,1024]^T -> Hb (bf16 gelu), K=1024
  gemm128r<0><<<dim3(FDIM/128, B_TOK/128, NZ), 256, 0, stream>>>(
      xb, DDIM, 0L, WinT, DDIM,
      Hb, nullptr, nullptr, tok, cnts);
  // out-proj, all 18 slots: [M,4096] x [1024,4096]^T -> Eout / gen_p (f32), K=4096
  gemm128r<1><<<dim3(DDIM/128, B_TOK/128, NZ), 256, 0, stream>>>(
      Hb, FDIM, BF, WoutT, FDIM,
      nullptr, Eout, gen_p, nullptr, cnts);

  combine_ln_kernel<<<B_TOK, 256, 0, stream>>>(
      x, moe_bias, Eout, gen_p, gb_out, pos, gates, gamma, beta, out);
}

// Round 10
// 899.497 us; speedup vs baseline: 1.2200x; 1.1315x over previous
//
#include <hip/hip_runtime.h>
#include <hip/hip_bf16.h>

#define B_TOK 2048
#define DDIM 1024
#define FDIM 4096
#define NE 16
#define NG 2
#define BD ((long)B_TOK * DDIM)

typedef unsigned short u16;
typedef __attribute__((ext_vector_type(8))) short bf16x8;   // 8 bf16 (4 VGPRs)
typedef __attribute__((ext_vector_type(4))) float f32x4;

// ---------- helpers ----------
__device__ inline u16 f2bf(float x) {           // RNE f32 -> bf16 bits
  union { float f; unsigned u; } v; v.f = x;
  return (u16)((v.u + 0x7fffu + ((v.u >> 16) & 1u)) >> 16);
}
__device__ inline float bfround(float x) {      // f32 -> bf16 -> f32 (matches astype(bf16))
  union { float f; unsigned u; } v; v.f = x;
  v.u = ((v.u + 0x7fffu + ((v.u >> 16) & 1u)) >> 16) << 16;
  return v.f;
}
// Abramowitz-Stegun 7.1.26 erf, |eps| <= 1.5e-7
__device__ inline float fast_erf(float x) {
  float ax = fabsf(x);
  float t = __builtin_amdgcn_rcpf(1.0f + 0.3275911f * ax);
  float poly = t * (0.254829592f + t * (-0.284496736f + t * (1.421413741f +
               t * (-1.453152027f + t * 1.061405429f))));
  float r = 1.0f - poly * __expf(-ax * ax);
  return copysignf(r, x);
}
__device__ inline float gelu_exact(float x) {
  return 0.5f * x * (1.0f + fast_erf(x * 0.70710678118654752440f));
}
__device__ inline void gload16(const void* g, void* l) {
  // LDS dest is wave-uniform base; HW adds lane*16 (guide m104/m108).
  __builtin_amdgcn_global_load_lds((const __attribute__((address_space(1))) void*)g,
                                   (__attribute__((address_space(3))) void*)l, 16, 0, 0);
}
__device__ inline float waveSum(float v) {
  v += __shfl_down(v, 32); v += __shfl_down(v, 16); v += __shfl_down(v, 8);
  v += __shfl_down(v, 4);  v += __shfl_down(v, 2);  v += __shfl_down(v, 1);
  return v;
}

// ---------- gating + loss partials ----------
__global__ __launch_bounds__(256) void gating_kernel(
    const float* __restrict__ logits, const int* __restrict__ masks,
    float* __restrict__ gates, float* __restrict__ loss)
{
  const int b = blockIdx.x * 256 + threadIdx.x;       // grid 8 x 256 == 2048
  const int lane = threadIdx.x & 63;
  const float* lr = logits + (long)b * NE;
  const int*   mr = masks  + (long)b * NE;
  float raw[NE]; int mk[NE];
  float mx = -1e30f;
#pragma unroll
  for (int e = 0; e < NE; ++e) { raw[e] = lr[e]; mx = fmaxf(mx, raw[e]); }
  float s = 0.f;
#pragma unroll
  for (int e = 0; e < NE; ++e) { raw[e] = expf(raw[e] - mx); s += raw[e]; }
  float inv = 1.0f / s;
#pragma unroll
  for (int e = 0; e < NE; ++e) raw[e] *= inv;
  float gs = 0.f;
#pragma unroll
  for (int e = 0; e < NE; ++e) { mk[e] = (mr[e] == 1); gs += mk[e] ? raw[e] : 0.f; }
  float ginv = 1.0f / (gs + 1e-9f);
  float* gr = gates + (long)b * NE;
#pragma unroll
  for (int e = 0; e < NE; ++e) gr[e] = (mk[e] ? raw[e] : 0.f) * ginv;
#pragma unroll
  for (int e = 0; e < NE; ++e) {
    float cs = waveSum(raw[e]);
    float cc = waveSum(mk[e] ? 1.f : 0.f);
    if (lane == 0) { atomicAdd(&loss[e], cs); atomicAdd(&loss[NE + e], cc); }
  }
  float t = waveSum(gs);
  if (lane == 0) atomicAdd(&loss[32], t);
}

__global__ void finalize_loss(const float* __restrict__ loss, float* __restrict__ out2) {
  if (threadIdx.x == 0) {
    float aug = 0.f;
    for (int e = 0; e < NE; ++e)
      aug += (loss[e] / (float)B_TOK) * (loss[NE + e] / (float)B_TOK);
    aug *= (1.0f / NE);
    float s = loss[32] / (float)B_TOK;
    out2[0] = aug;
    out2[1] = (1.f - s) * (1.f - s);
  }
}

// ---------- deterministic per-expert token compaction + inverse map ----------
__global__ __launch_bounds__(256) void compact_kernel(
    const int* __restrict__ masks, int* __restrict__ tok,
    int* __restrict__ pos, int* __restrict__ cnts)
{
  const int e = blockIdx.x, tid = threadIdx.x;
  const int lane = tid & 63, wave = tid >> 6;
  __shared__ int wcnt[4];
  __shared__ int runbase;
  if (tid == 0) runbase = 0;
  __syncthreads();
  for (int b0 = 0; b0 < B_TOK; b0 += 256) {
    int b = b0 + tid;
    int m = (masks[(long)b * NE + e] == 1);
    unsigned long long bal = __ballot(m);
    int pre = __popcll(bal & ((1ull << lane) - 1ull));
    if (lane == 0) wcnt[wave] = __popcll(bal);
    __syncthreads();
    int base = runbase;
    for (int w = 0; w < wave; ++w) base += wcnt[w];
    if (m) {
      int p = base + pre;
      tok[(e << 11) + p] = b;
      pos[(long)b * NE + e] = p;
    } else {
      pos[(long)b * NE + e] = -1;
    }
    __syncthreads();
    if (tid == 0) runbase += wcnt[0] + wcnt[1] + wcnt[2] + wcnt[3];
    __syncthreads();
  }
  const int cnt = runbase;
  const int cnt_pad = (cnt + 127) & ~127;
  for (int i = cnt + tid; i < cnt_pad; i += 256)
    tok[(e << 11) + i] = 0;          // safe row; pad output rows never read
  if (tid == 0) { cnts[e] = cnt; cnts[NE + e] = cnt_pad; }
}

// ---------- x f32 -> bf16 ----------
__global__ __launch_bounds__(256) void cvt_x_kernel(const float* __restrict__ x, u16* __restrict__ xb) {
  long i = ((long)blockIdx.x * 256 + threadIdx.x) * 4;
  float4 v = *(const float4*)&x[i];
  ushort4 o; o.x = f2bf(v.x); o.y = f2bf(v.y); o.z = f2bf(v.z); o.w = f2bf(v.w);
  *(ushort4*)&xb[i] = o;
}

// ---------- moe bias: moe_bias[b,d] = sum_e gates[b,e]*eb[e,d] ----------
__global__ __launch_bounds__(256) void bias_init_kernel(
    const float* __restrict__ gates, const float* __restrict__ eb,
    float* __restrict__ moe_bias)
{
  long i = (long)blockIdx.x * 256 + threadIdx.x;       // grid 8192 -> B*D
  int b = (int)(i >> 10), d = (int)(i & 1023);
  const float* gr = gates + (long)b * NE;
  float s = 0.f;
#pragma unroll
  for (int e = 0; e < NE; ++e) s += gr[e] * eb[e * DDIM + d];
  moe_bias[i] = s;
}

// ---------- transpose + f32->bf16: src [R,C] -> dst [C,R] ----------
__global__ __launch_bounds__(256) void transpose_cvt(
    const float* __restrict__ src, u16* __restrict__ dst,
    int R, int C, long sZ, long dZ)
{
  __shared__ float t[64][65];
  const float* s = src + (long)blockIdx.z * sZ;
  u16* d = dst + (long)blockIdx.z * dZ;
  const int c0 = blockIdx.x * 64, r0 = blockIdx.y * 64;
  const int tid = threadIdx.x;
#pragma unroll
  for (int it = 0; it < 4; ++it) {
    int idx = tid + it * 256;
    int r = idx >> 4, cq = (idx & 15) * 4;
    float4 v = *(const float4*)&s[(long)(r0 + r) * C + c0 + cq];
    t[r][cq] = v.x; t[r][cq + 1] = v.y; t[r][cq + 2] = v.z; t[r][cq + 3] = v.w;
  }
  __syncthreads();
#pragma unroll
  for (int it = 0; it < 4; ++it) {
    int idx = tid + it * 256;
    int c = idx >> 4, rq = (idx & 15) * 4;
    ushort4 o;
    o.x = f2bf(t[rq][c]); o.y = f2bf(t[rq+1][c]); o.z = f2bf(t[rq+2][c]); o.w = f2bf(t[rq+3][c]);
    *(ushort4*)&d[(long)(c0 + c) * R + r0 + rq] = o;
  }
}

// ---------- 128x128 bf16 MFMA GEMM — r5-validated 3-buffer counted-vmcnt ring.
// klen is a RUNTIME arg on purpose: constexpr K caused full t-loop unroll in r9
// (VGPR 84->100, occupancy 31->15%, dur 228->426us). Do not make it constexpr.
// PROJ 0 (in-proj, klen=1024): z<16 A rows gathered via tok (xb); z>=16 identity
//   (general experts). Epilogue: Hb[z] = bf16(gelu(acc)).
// PROJ 1 (out-proj, klen=4096): A = Hb[z] compact rows; epilogue: z<16 -> Eout[z],
//   z>=16 -> gen_p[z-16] (f32, pure writes; no pre-zero needed).
template<int PROJ>
__global__ __launch_bounds__(256) void gemm128r(
    const u16* __restrict__ A, int lda, long aZ,
    const u16* __restrict__ Bm, int ldb, int klen,
    u16* __restrict__ H,
    float* __restrict__ Eout, float* __restrict__ genp,
    const int* __restrict__ tok, const int* __restrict__ cnts)
{
  // bijective chunked XCD swizzle (T divisible by 8 by construction)
  int lin = ((int)blockIdx.z * gridDim.y + blockIdx.y) * gridDim.x + blockIdx.x;
  const int T = gridDim.x * gridDim.y * gridDim.z;
  lin = (lin & 7) * (T >> 3) + (lin >> 3);
  const int bx = lin % gridDim.x;
  const int rest = lin / gridDim.x;
  const int by = rest % gridDim.y;
  const int z  = rest / gridDim.y;

  const int m0 = by * 128, n0 = bx * 128;
  if (z < NE && m0 >= cnts[NE + z]) return;    // routed: beyond padded count

  __shared__ u16 sA[3][128 * 32];
  __shared__ u16 sB[3][128 * 32];
  const u16* Az = (PROJ == 0) ? A : A + (long)z * aZ;
  const u16* Bz = Bm + (long)z * ((long)DDIM * FDIM);
  const int tid = threadIdx.x, lane = tid & 63, wave = tid >> 6;

  // staging: linear LDS, 2 passes of 16B/thread per operand
  const int off = tid * 16;            // byte offset in 8KB tile (pass 0)
  const int sr  = off >> 6;            // row 0..63 (64B per row of 32 bf16)
  const int ske = (off & 63) >> 1;     // k element offset within row
  int arow0 = m0 + sr, arow1 = m0 + sr + 64;
  if (PROJ == 0 && z < NE) {           // gather source rows (per-lane global ok)
    const int* tz = tok + (z << 11);
    arow0 = tz[arow0]; arow1 = tz[arow1];
  }
  const u16* gA0 = Az + (long)arow0 * lda + ske;
  const u16* gA1 = Az + (long)arow1 * lda + ske;
  const u16* gB0 = Bz + (long)(n0 + sr) * ldb + ske;
  const u16* gB1 = Bz + (long)(n0 + sr + 64) * ldb + ske;

  const int wr = wave >> 1, wc = wave & 1;            // 2x2 waves of 64x64
  const int fr = lane & 15, fk = (lane >> 4) * 8;
  const int rAo = (wr * 64 + fr) * 32 + fk;
  const int rBo = (wc * 64 + fr) * 32 + fk;

  f32x4 zero = {0.f, 0.f, 0.f, 0.f};
  f32x4 acc[4][4];
#pragma unroll
  for (int m = 0; m < 4; ++m)
#pragma unroll
    for (int n = 0; n < 4; ++n) acc[m][n] = zero;

  auto STAGE = [&](u16* dA, u16* dB, int t) {
    const int kk = t << 5;
    gload16(gA0 + kk, dA + wave * 512);
    gload16(gA1 + kk, dA + 2048 + wave * 512);
    gload16(gB0 + kk, dB + wave * 512);
    gload16(gB1 + kk, dB + 2048 + wave * 512);
  };
  auto COMPUTE = [&](const u16* bA, const u16* bB) {
    bf16x8 av[4], bv[4];
#pragma unroll
    for (int m = 0; m < 4; ++m) av[m] = *(const bf16x8*)(bA + rAo + m * 512);
#pragma unroll
    for (int n = 0; n < 4; ++n) bv[n] = *(const bf16x8*)(bB + rBo + n * 512);
#pragma unroll
    for (int m = 0; m < 4; ++m)
#pragma unroll
      for (int n = 0; n < 4; ++n)
        acc[m][n] = __builtin_amdgcn_mfma_f32_16x16x32_bf16(av[m], bv[n], acc[m][n], 0, 0, 0);
  };

  // r5-validated pipeline: stage K-step (t+2), counted vmcnt(8) keeps two tiles
  // in flight (never 0 in steady state), barrier, compute K-step t.
#define PIPE(SA, SB, KIDX, CA, CB)                                   \
  STAGE(SA, SB, KIDX);                                               \
  asm volatile("s_waitcnt vmcnt(8)" ::: "memory");                   \
  __builtin_amdgcn_s_barrier();                                      \
  asm volatile("" ::: "memory");                                     \
  COMPUTE(CA, CB);                                                   \
  asm volatile("" ::: "memory");                                     \
  __builtin_amdgcn_s_barrier();                                      \
  asm volatile("" ::: "memory");

  const int nt = klen >> 5;            // (nt-2) % 3 == 0 by construction
  STAGE(sA[0], sB[0], 0);
  STAGE(sA[1], sB[1], 1);
  for (int t = 0; t + 2 < nt; t += 3) {
    PIPE(sA[2], sB[2], t + 2, sA[0], sB[0]);
    PIPE(sA[0], sB[0], t + 3, sA[1], sB[1]);
    PIPE(sA[1], sB[1], t + 4, sA[2], sB[2]);
  }
  asm volatile("s_waitcnt vmcnt(4)" ::: "memory");
  __builtin_amdgcn_s_barrier();
  asm volatile("" ::: "memory");
  COMPUTE(sA[0], sB[0]);               // K-step nt-2
  asm volatile("s_waitcnt vmcnt(0)" ::: "memory");
  __builtin_amdgcn_s_barrier();
  asm volatile("" ::: "memory");
  COMPUTE(sA[1], sB[1]);               // K-step nt-1
#undef PIPE

  // epilogue: C/D map col=lane&15, row=(lane>>4)*4+j  (guide m89/m91)
  const int er = m0 + wr * 64 + (lane >> 4) * 4;
  const int ec = n0 + wc * 64 + fr;
  if (PROJ == 0) {
    u16* Hz = H + (long)z * ((long)B_TOK * FDIM);
#pragma unroll
    for (int m = 0; m < 4; ++m)
#pragma unroll
      for (int n = 0; n < 4; ++n) {
        f32x4 v = acc[m][n];
        int rb = er + m * 16, cb = ec + n * 16;
#pragma unroll
        for (int j = 0; j < 4; ++j)
          Hz[(long)(rb + j) * FDIM + cb] = f2bf(gelu_exact(v[j]));
      }
  } else {
    float* Cz = (z < NE) ? (Eout + (long)z * BD) : (genp + (long)(z - NE) * BD);
#pragma unroll
    for (int m = 0; m < 4; ++m)
#pragma unroll
      for (int n = 0; n < 4; ++n) {
        f32x4 v = acc[m][n];
        int rb = er + m * 16, cb = ec + n * 16;
#pragma unroll
        for (int j = 0; j < 4; ++j)
          Cz[(long)(rb + j) * DDIM + cb] = v[j];
      }
  }
}

// ---------- combine (gate-weighted gather) + general + residual + LayerNorm ----------
__global__ __launch_bounds__(256) void combine_ln_kernel(
    const float* __restrict__ x, const float* __restrict__ moe_bias,
    const float* __restrict__ Eout, const float* __restrict__ gen_p,
    const float* __restrict__ gb,
    const int* __restrict__ pos, const float* __restrict__ gates,
    const float* __restrict__ gamma, const float* __restrict__ beta,
    float* __restrict__ out)
{
  const int b = blockIdx.x, tid = threadIdx.x;
  const int lane = tid & 63, wave = tid >> 6;
  const long base = (long)b * DDIM;
  __shared__ int posr[NE];
  __shared__ float gr[NE];
  __shared__ float red[4];
  if (tid < NE) { posr[tid] = pos[(long)b * NE + tid]; gr[tid] = gates[(long)b * NE + tid]; }
  __syncthreads();
  float y[4];
  float ls = 0.f;
#pragma unroll
  for (int i = 0; i < 4; ++i) {
    int d = tid + i * 256;
    long idx = base + d;
    float moe = moe_bias[idx];
#pragma unroll
    for (int e = 0; e < NE; ++e) {
      int p = posr[e];                                  // block-uniform -> no divergence
      if (p >= 0) moe += gr[e] * Eout[((long)e * B_TOK + p) * DDIM + d];
    }
    moe = bfround(moe);                                 // matches ref's bf16 cast of moe_out
    float ge = gb[d] + gb[DDIM + d] + gen_p[idx] + gen_p[BD + idx];
    y[i] = moe + ge + x[idx];
    ls += y[i];
  }
  float t = waveSum(ls);
  if (lane == 0) red[wave] = t;
  __syncthreads();
  float mean = (red[0] + red[1] + red[2] + red[3]) * (1.0f / DDIM);
  __syncthreads();
  float vs = 0.f;
#pragma unroll
  for (int i = 0; i < 4; ++i) { float d2 = y[i] - mean; vs += d2 * d2; }
  t = waveSum(vs);
  if (lane == 0) red[wave] = t;
  __syncthreads();
  float var = (red[0] + red[1] + red[2] + red[3]) * (1.0f / DDIM);
  float inv = rsqrtf(var + 1e-5f);
#pragma unroll
  for (int i = 0; i < 4; ++i) {
    int d = tid + i * 256;
    out[base + d] = (y[i] - mean) * inv * gamma[d] + beta[d];
  }
}

// ---------- orchestration ----------
extern "C" void kernel_launch(void* const* d_in, const int* in_sizes, int n_in,
                              void* d_out, int out_size, void* d_ws, size_t ws_size,
                              hipStream_t stream)
{
  const float* x      = (const float*)d_in[0];
  const float* logits = (const float*)d_in[1];
  const int*   masks  = (const int*)d_in[2];
  const float* ew_in  = (const float*)d_in[3];
  const float* ew_out = (const float*)d_in[4];
  const float* eb_out = (const float*)d_in[5];
  const float* gw_in  = (const float*)d_in[6];
  const float* gw_out = (const float*)d_in[7];
  const float* gb_out = (const float*)d_in[8];
  const float* gamma  = (const float*)d_in[9];
  const float* beta   = (const float*)d_in[10];
  float* out = (float*)d_out;

  char* w = (char*)d_ws;
  size_t off = 0;
  auto alloc = [&](size_t bytes) -> void* {
    off = (off + 4095) & ~(size_t)4095;
    void* p = w + off; off += bytes; return p;
  };
  const long DF = (long)DDIM * FDIM;          // 4.19M elems
  const long BF = (long)B_TOK * FDIM;         // 8.39M elems
  const int  NZ = NE + NG;                    // 18 unified expert slots

  float* gates    = (float*)alloc((size_t)B_TOK * NE * 4);
  float* loss     = (float*)alloc(64 * 4);
  int*   tok      = (int*)alloc((size_t)NE * B_TOK * 4);
  int*   pos      = (int*)alloc((size_t)B_TOK * NE * 4);
  int*   cnts     = (int*)alloc(2 * NE * 4);
  u16*   xb       = (u16*)alloc((size_t)BD * 2);
  float* moe_bias = (float*)alloc((size_t)BD * 4);
  float* gen_p    = (float*)alloc((size_t)NG * BD * 4);          // 2 slices (per g)
  float* Eout     = (float*)alloc((size_t)NE * BD * 4);          // per-expert compact f32
  u16*   WinT     = (u16*)alloc((size_t)NZ * DF * 2);            // [F,D] per slot
  u16*   WoutT    = (u16*)alloc((size_t)NZ * DF * 2);            // [D,F] per slot
  u16*   Hb       = (u16*)alloc((size_t)NZ * BF * 2);            // gelu acts per slot

  hipMemsetAsync(loss, 0, 64 * 4, stream);
  gating_kernel<<<8, 256, 0, stream>>>(logits, masks, gates, loss);
  finalize_loss<<<1, 64, 0, stream>>>(loss, out + BD);
  compact_kernel<<<NE, 256, 0, stream>>>(masks, tok, pos, cnts);
  cvt_x_kernel<<<2048, 256, 0, stream>>>(x, xb);
  bias_init_kernel<<<8192, 256, 0, stream>>>(gates, eb_out, moe_bias);

  // all weight transposes up front (routed slots 0..15, general 16..17)
  transpose_cvt<<<dim3(FDIM/64, DDIM/64, NE), 256, 0, stream>>>(
      ew_in, WinT, DDIM, FDIM, DF, DF);
  transpose_cvt<<<dim3(FDIM/64, DDIM/64, NG), 256, 0, stream>>>(
      gw_in, WinT + (long)NE * DF, DDIM, FDIM, DF, DF);
  transpose_cvt<<<dim3(DDIM/64, FDIM/64, NE), 256, 0, stream>>>(
      ew_out, WoutT, FDIM, DDIM, DF, DF);
  transpose_cvt<<<dim3(DDIM/64, FDIM/64, NG), 256, 0, stream>>>(
      gw_out, WoutT + (long)NE * DF, FDIM, DDIM, DF, DF);

  // in-proj, all 18 slots: [M,1024] x [4096,1024]^T -> Hb (bf16 gelu), K=1024
  gemm128r<0><<<dim3(FDIM/128, B_TOK/128, NZ), 256, 0, stream>>>(
      xb, DDIM, 0L, WinT, DDIM, DDIM,
      Hb, nullptr, nullptr, tok, cnts);
  // out-proj, all 18 slots: [M,4096] x [1024,4096]^T -> Eout / gen_p (f32), K=4096
  gemm128r<1><<<dim3(DDIM/128, B_TOK/128, NZ), 256, 0, stream>>>(
      Hb, FDIM, BF, WoutT, FDIM, FDIM,
      nullptr, Eout, gen_p, nullptr, cnts);

  combine_ln_kernel<<<B_TOK, 256, 0, stream>>>(
      x, moe_bias, Eout, gen_p, gb_out, pos, gates, gamma, beta, out);
}

// Round 11
// 762.455 us; speedup vs baseline: 1.4393x; 1.1797x over previous
//
#include <hip/hip_runtime.h>
#include <hip/hip_bf16.h>

#define B_TOK 2048
#define DDIM 1024
#define FDIM 4096
#define NE 16
#define NG 2
#define BD ((long)B_TOK * DDIM)

typedef unsigned short u16;
typedef __attribute__((ext_vector_type(8))) short bf16x8;   // 8 bf16 (4 VGPRs)
typedef __attribute__((ext_vector_type(4))) float f32x4;

// ---------- helpers ----------
__device__ inline u16 f2bf(float x) {           // RNE f32 -> bf16 bits
  union { float f; unsigned u; } v; v.f = x;
  return (u16)((v.u + 0x7fffu + ((v.u >> 16) & 1u)) >> 16);
}
__device__ inline float bfround(float x) {      // f32 -> bf16 -> f32 (matches astype(bf16))
  union { float f; unsigned u; } v; v.f = x;
  v.u = ((v.u + 0x7fffu + ((v.u >> 16) & 1u)) >> 16) << 16;
  return v.f;
}
// Abramowitz-Stegun 7.1.26 erf, |eps| <= 1.5e-7
__device__ inline float fast_erf(float x) {
  float ax = fabsf(x);
  float t = __builtin_amdgcn_rcpf(1.0f + 0.3275911f * ax);
  float poly = t * (0.254829592f + t * (-0.284496736f + t * (1.421413741f +
               t * (-1.453152027f + t * 1.061405429f))));
  float r = 1.0f - poly * __expf(-ax * ax);
  return copysignf(r, x);
}
__device__ inline float gelu_exact(float x) {
  return 0.5f * x * (1.0f + fast_erf(x * 0.70710678118654752440f));
}
__device__ inline void gload16(const void* g, void* l) {
  // LDS dest is wave-uniform base; HW adds lane*16 (guide m104/m108).
  __builtin_amdgcn_global_load_lds((const __attribute__((address_space(1))) void*)g,
                                   (__attribute__((address_space(3))) void*)l, 16, 0, 0);
}
__device__ inline float waveSum(float v) {
  v += __shfl_down(v, 32); v += __shfl_down(v, 16); v += __shfl_down(v, 8);
  v += __shfl_down(v, 4);  v += __shfl_down(v, 2);  v += __shfl_down(v, 1);
  return v;
}

// ---------- gating + loss partials ----------
__global__ __launch_bounds__(256) void gating_kernel(
    const float* __restrict__ logits, const int* __restrict__ masks,
    float* __restrict__ gates, float* __restrict__ loss)
{
  const int b = blockIdx.x * 256 + threadIdx.x;       // grid 8 x 256 == 2048
  const int lane = threadIdx.x & 63;
  const float* lr = logits + (long)b * NE;
  const int*   mr = masks  + (long)b * NE;
  float raw[NE]; int mk[NE];
  float mx = -1e30f;
#pragma unroll
  for (int e = 0; e < NE; ++e) { raw[e] = lr[e]; mx = fmaxf(mx, raw[e]); }
  float s = 0.f;
#pragma unroll
  for (int e = 0; e < NE; ++e) { raw[e] = expf(raw[e] - mx); s += raw[e]; }
  float inv = 1.0f / s;
#pragma unroll
  for (int e = 0; e < NE; ++e) raw[e] *= inv;
  float gs = 0.f;
#pragma unroll
  for (int e = 0; e < NE; ++e) { mk[e] = (mr[e] == 1); gs += mk[e] ? raw[e] : 0.f; }
  float ginv = 1.0f / (gs + 1e-9f);
  float* gr = gates + (long)b * NE;
#pragma unroll
  for (int e = 0; e < NE; ++e) gr[e] = (mk[e] ? raw[e] : 0.f) * ginv;
#pragma unroll
  for (int e = 0; e < NE; ++e) {
    float cs = waveSum(raw[e]);
    float cc = waveSum(mk[e] ? 1.f : 0.f);
    if (lane == 0) { atomicAdd(&loss[e], cs); atomicAdd(&loss[NE + e], cc); }
  }
  float t = waveSum(gs);
  if (lane == 0) atomicAdd(&loss[32], t);
}

__global__ void finalize_loss(const float* __restrict__ loss, float* __restrict__ out2) {
  if (threadIdx.x == 0) {
    float aug = 0.f;
    for (int e = 0; e < NE; ++e)
      aug += (loss[e] / (float)B_TOK) * (loss[NE + e] / (float)B_TOK);
    aug *= (1.0f / NE);
    float s = loss[32] / (float)B_TOK;
    out2[0] = aug;
    out2[1] = (1.f - s) * (1.f - s);
  }
}

// ---------- deterministic per-expert token compaction + inverse map ----------
__global__ __launch_bounds__(256) void compact_kernel(
    const int* __restrict__ masks, int* __restrict__ tok,
    int* __restrict__ pos, int* __restrict__ cnts)
{
  const int e = blockIdx.x, tid = threadIdx.x;
  const int lane = tid & 63, wave = tid >> 6;
  __shared__ int wcnt[4];
  __shared__ int runbase;
  if (tid == 0) runbase = 0;
  __syncthreads();
  for (int b0 = 0; b0 < B_TOK; b0 += 256) {
    int b = b0 + tid;
    int m = (masks[(long)b * NE + e] == 1);
    unsigned long long bal = __ballot(m);
    int pre = __popcll(bal & ((1ull << lane) - 1ull));
    if (lane == 0) wcnt[wave] = __popcll(bal);
    __syncthreads();
    int base = runbase;
    for (int w = 0; w < wave; ++w) base += wcnt[w];
    if (m) {
      int p = base + pre;
      tok[(e << 11) + p] = b;
      pos[(long)b * NE + e] = p;
    } else {
      pos[(long)b * NE + e] = -1;
    }
    __syncthreads();
    if (tid == 0) runbase += wcnt[0] + wcnt[1] + wcnt[2] + wcnt[3];
    __syncthreads();
  }
  const int cnt = runbase;
  const int cnt_pad = (cnt + 127) & ~127;
  for (int i = cnt + tid; i < cnt_pad; i += 256)
    tok[(e << 11) + i] = 0;          // safe row; pad output rows never read
  if (tid == 0) { cnts[e] = cnt; cnts[NE + e] = cnt_pad; }
}

// ---------- x f32 -> bf16 ----------
__global__ __launch_bounds__(256) void cvt_x_kernel(const float* __restrict__ x, u16* __restrict__ xb) {
  long i = ((long)blockIdx.x * 256 + threadIdx.x) * 4;
  float4 v = *(const float4*)&x[i];
  ushort4 o; o.x = f2bf(v.x); o.y = f2bf(v.y); o.z = f2bf(v.z); o.w = f2bf(v.w);
  *(ushort4*)&xb[i] = o;
}

// ---------- moe bias: moe_bias[b,d] = sum_e gates[b,e]*eb[e,d] ----------
__global__ __launch_bounds__(256) void bias_init_kernel(
    const float* __restrict__ gates, const float* __restrict__ eb,
    float* __restrict__ moe_bias)
{
  long i = (long)blockIdx.x * 256 + threadIdx.x;       // grid 8192 -> B*D
  int b = (int)(i >> 10), d = (int)(i & 1023);
  const float* gr = gates + (long)b * NE;
  float s = 0.f;
#pragma unroll
  for (int e = 0; e < NE; ++e) s += gr[e] * eb[e * DDIM + d];
  moe_bias[i] = s;
}

// ---------- transpose + f32->bf16: src [R,C] -> dst [C,R] ----------
__global__ __launch_bounds__(256) void transpose_cvt(
    const float* __restrict__ src, u16* __restrict__ dst,
    int R, int C, long sZ, long dZ)
{
  __shared__ float t[64][65];
  const float* s = src + (long)blockIdx.z * sZ;
  u16* d = dst + (long)blockIdx.z * dZ;
  const int c0 = blockIdx.x * 64, r0 = blockIdx.y * 64;
  const int tid = threadIdx.x;
#pragma unroll
  for (int it = 0; it < 4; ++it) {
    int idx = tid + it * 256;
    int r = idx >> 4, cq = (idx & 15) * 4;
    float4 v = *(const float4*)&s[(long)(r0 + r) * C + c0 + cq];
    t[r][cq] = v.x; t[r][cq + 1] = v.y; t[r][cq + 2] = v.z; t[r][cq + 3] = v.w;
  }
  __syncthreads();
#pragma unroll
  for (int it = 0; it < 4; ++it) {
    int idx = tid + it * 256;
    int c = idx >> 4, rq = (idx & 15) * 4;
    ushort4 o;
    o.x = f2bf(t[rq][c]); o.y = f2bf(t[rq+1][c]); o.z = f2bf(t[rq+2][c]); o.w = f2bf(t[rq+3][c]);
    *(ushort4*)&d[(long)(c0 + c) * R + r0 + rq] = o;
  }
}

// ---------- 128x128 bf16 MFMA GEMM — r5-validated 3-buffer counted-vmcnt ring,
// + 4x4 super-tile raster within each z (bijective; chunk alignment preserved:
// 16 z per dispatch => each XCD chunk covers exactly 2 experts).
// klen is a RUNTIME arg on purpose (constexpr K unrolled the t-loop in r9:
// VGPR 84->100, occupancy halved). Do not make it constexpr.
// MODE 0 (in-proj): A rows gathered via tok (tok!=null) else identity.
//   Epilogue: H[zi] = bf16(gelu(acc)).
// MODE 1 (out-proj routed): A = H[zi] compact rows, full-K. C[ebase+zi] = acc.
// MODE 2 (out-proj general): bz = g*4+ks, K-split 4, klen=FDIM/4.
//   C[bz] = acc (disjoint per-slice tiles -> pure write).
template<int MODE>
__global__ __launch_bounds__(256) void gemm128(
    const u16* __restrict__ A, int lda, long aZ,
    const u16* __restrict__ Bm, int ldb, long bZ,
    int klen,
    u16* __restrict__ H, long hZ,
    float* __restrict__ C, long cZ,
    const int* __restrict__ tok, const int* __restrict__ cnts, int ebase)
{
  // bijective chunked XCD swizzle (T divisible by 8 by construction)
  int lin = ((int)blockIdx.z * gridDim.y + blockIdx.y) * gridDim.x + blockIdx.x;
  const int T = gridDim.x * gridDim.y * gridDim.z;
  lin = (lin & 7) * (T >> 3) + (lin >> 3);
  // 4x4 super-tile decode within z: consecutive lin traverse a 4x4 tile block
  // (gridDim.x, gridDim.y both divisible by 4 for all launches here).
  const int PZ = gridDim.x * gridDim.y;
  const int bz = lin / PZ;
  const int r  = lin - bz * PZ;
  const int nSx = gridDim.x >> 2;
  const int st = r >> 4, pos = r & 15;
  const int bx = ((st % nSx) << 2) + (pos & 3);
  const int by = ((st / nSx) << 2) + (pos >> 2);

  const int zi = (MODE == 2) ? (bz >> 2) : bz;
  const int ks = (MODE == 2) ? (bz & 3) * klen : 0;
  const int m0 = by * 128, n0 = bx * 128;
  if (MODE != 2 && cnts && m0 >= cnts[NE + ebase + zi]) return;

  __shared__ u16 sA[3][128 * 32];
  __shared__ u16 sB[3][128 * 32];
  const u16* Az = A + (long)zi * aZ;
  const u16* Bz = Bm + (long)zi * bZ;
  const int tid = threadIdx.x, lane = tid & 63, wave = tid >> 6;

  // staging: linear LDS, 2 passes of 16B/thread per operand
  const int off = tid * 16;            // byte offset in 8KB tile (pass 0)
  const int sr  = off >> 6;            // row 0..63 (64B per row of 32 bf16)
  const int ske = (off & 63) >> 1;     // k element offset within row
  int arow0 = m0 + sr, arow1 = m0 + sr + 64;
  if (MODE == 0 && tok) {              // gather source rows (per-lane global ok)
    const int* tz = tok + ((ebase + zi) << 11);
    arow0 = tz[arow0]; arow1 = tz[arow1];
  }
  const u16* gA0 = Az + (long)arow0 * lda + ks + ske;
  const u16* gA1 = Az + (long)arow1 * lda + ks + ske;
  const u16* gB0 = Bz + (long)(n0 + sr) * ldb + ks + ske;
  const u16* gB1 = Bz + (long)(n0 + sr + 64) * ldb + ks + ske;

  const int wr = wave >> 1, wc = wave & 1;            // 2x2 waves of 64x64
  const int fr = lane & 15, fk = (lane >> 4) * 8;
  const int rAo = (wr * 64 + fr) * 32 + fk;
  const int rBo = (wc * 64 + fr) * 32 + fk;

  f32x4 zero = {0.f, 0.f, 0.f, 0.f};
  f32x4 acc[4][4];
#pragma unroll
  for (int m = 0; m < 4; ++m)
#pragma unroll
    for (int n = 0; n < 4; ++n) acc[m][n] = zero;

  auto STAGE = [&](u16* dA, u16* dB, int t) {
    const int kk = t << 5;
    gload16(gA0 + kk, dA + wave * 512);
    gload16(gA1 + kk, dA + 2048 + wave * 512);
    gload16(gB0 + kk, dB + wave * 512);
    gload16(gB1 + kk, dB + 2048 + wave * 512);
  };
  auto COMPUTE = [&](const u16* bA, const u16* bB) {
    bf16x8 av[4], bv[4];
#pragma unroll
    for (int m = 0; m < 4; ++m) av[m] = *(const bf16x8*)(bA + rAo + m * 512);
#pragma unroll
    for (int n = 0; n < 4; ++n) bv[n] = *(const bf16x8*)(bB + rBo + n * 512);
#pragma unroll
    for (int m = 0; m < 4; ++m)
#pragma unroll
      for (int n = 0; n < 4; ++n)
        acc[m][n] = __builtin_amdgcn_mfma_f32_16x16x32_bf16(av[m], bv[n], acc[m][n], 0, 0, 0);
  };

  // r5-validated pipeline: stage K-step (t+2), counted vmcnt(8) keeps two tiles
  // in flight (never 0 in steady state), barrier, compute K-step t.
#define PIPE(SA, SB, KIDX, CA, CB)                                   \
  STAGE(SA, SB, KIDX);                                               \
  asm volatile("s_waitcnt vmcnt(8)" ::: "memory");                   \
  __builtin_amdgcn_s_barrier();                                      \
  asm volatile("" ::: "memory");                                     \
  COMPUTE(CA, CB);                                                   \
  asm volatile("" ::: "memory");                                     \
  __builtin_amdgcn_s_barrier();                                      \
  asm volatile("" ::: "memory");

  const int nt = klen >> 5;            // (nt-2) % 3 == 0 by construction
  STAGE(sA[0], sB[0], 0);
  STAGE(sA[1], sB[1], 1);
  for (int t = 0; t + 2 < nt; t += 3) {
    PIPE(sA[2], sB[2], t + 2, sA[0], sB[0]);
    PIPE(sA[0], sB[0], t + 3, sA[1], sB[1]);
    PIPE(sA[1], sB[1], t + 4, sA[2], sB[2]);
  }
  asm volatile("s_waitcnt vmcnt(4)" ::: "memory");
  __builtin_amdgcn_s_barrier();
  asm volatile("" ::: "memory");
  COMPUTE(sA[0], sB[0]);               // K-step nt-2
  asm volatile("s_waitcnt vmcnt(0)" ::: "memory");
  __builtin_amdgcn_s_barrier();
  asm volatile("" ::: "memory");
  COMPUTE(sA[1], sB[1]);               // K-step nt-1
#undef PIPE

  // epilogue: C/D map col=lane&15, row=(lane>>4)*4+j  (guide m89/m91)
  const int er = m0 + wr * 64 + (lane >> 4) * 4;
  const int ec = n0 + wc * 64 + fr;
  if (MODE == 0) {
    u16* Hz = H + (long)zi * hZ;
#pragma unroll
    for (int m = 0; m < 4; ++m)
#pragma unroll
      for (int n = 0; n < 4; ++n) {
        f32x4 v = acc[m][n];
        int rb = er + m * 16, cb = ec + n * 16;
#pragma unroll
        for (int j = 0; j < 4; ++j)
          Hz[(long)(rb + j) * FDIM + cb] = f2bf(gelu_exact(v[j]));
      }
  } else if (MODE == 1) {
    float* Cz = C + (long)(ebase + zi) * cZ;
#pragma unroll
    for (int m = 0; m < 4; ++m)
#pragma unroll
      for (int n = 0; n < 4; ++n) {
        f32x4 v = acc[m][n];
        int rb = er + m * 16, cb = ec + n * 16;
#pragma unroll
        for (int j = 0; j < 4; ++j)
          Cz[(long)(rb + j) * DDIM + cb] = v[j];
      }
  } else {
    float* Cz = C + (long)bz * cZ;     // private (g,ks) slice, disjoint -> pure write
#pragma unroll
    for (int m = 0; m < 4; ++m)
#pragma unroll
      for (int n = 0; n < 4; ++n) {
        f32x4 v = acc[m][n];
        int rb = er + m * 16, cb = ec + n * 16;
#pragma unroll
        for (int j = 0; j < 4; ++j)
          Cz[(long)(rb + j) * DDIM + cb] = v[j];
      }
  }
}

// ---------- combine (gate-weighted gather) + general + residual + LayerNorm ----------
__global__ __launch_bounds__(256) void combine_ln_kernel(
    const float* __restrict__ x, const float* __restrict__ moe_bias,
    const float* __restrict__ Eout, const float* __restrict__ gen_p,
    const float* __restrict__ gb,
    const int* __restrict__ pos, const float* __restrict__ gates,
    const float* __restrict__ gamma, const float* __restrict__ beta,
    float* __restrict__ out)
{
  const int b = blockIdx.x, tid = threadIdx.x;
  const int lane = tid & 63, wave = tid >> 6;
  const long base = (long)b * DDIM;
  __shared__ int posr[NE];
  __shared__ float gr[NE];
  __shared__ float red[4];
  if (tid < NE) { posr[tid] = pos[(long)b * NE + tid]; gr[tid] = gates[(long)b * NE + tid]; }
  __syncthreads();
  float y[4];
  float ls = 0.f;
#pragma unroll
  for (int i = 0; i < 4; ++i) {
    int d = tid + i * 256;
    long idx = base + d;
    float moe = moe_bias[idx];
#pragma unroll
    for (int e = 0; e < NE; ++e) {
      int p = posr[e];                                  // block-uniform -> no divergence
      if (p >= 0) moe += gr[e] * Eout[((long)e * B_TOK + p) * DDIM + d];
    }
    moe = bfround(moe);                                 // matches ref's bf16 cast of moe_out
    float ge = gb[d] + gb[DDIM + d];
#pragma unroll
    for (int sl = 0; sl < 8; ++sl) ge += gen_p[(long)sl * BD + idx];
    y[i] = moe + ge + x[idx];
    ls += y[i];
  }
  float t = waveSum(ls);
  if (lane == 0) red[wave] = t;
  __syncthreads();
  float mean = (red[0] + red[1] + red[2] + red[3]) * (1.0f / DDIM);
  __syncthreads();
  float vs = 0.f;
#pragma unroll
  for (int i = 0; i < 4; ++i) { float d2 = y[i] - mean; vs += d2 * d2; }
  t = waveSum(vs);
  if (lane == 0) red[wave] = t;
  __syncthreads();
  float var = (red[0] + red[1] + red[2] + red[3]) * (1.0f / DDIM);
  float inv = rsqrtf(var + 1e-5f);
#pragma unroll
  for (int i = 0; i < 4; ++i) {
    int d = tid + i * 256;
    out[base + d] = (y[i] - mean) * inv * gamma[d] + beta[d];
  }
}

// ---------- orchestration ----------
extern "C" void kernel_launch(void* const* d_in, const int* in_sizes, int n_in,
                              void* d_out, int out_size, void* d_ws, size_t ws_size,
                              hipStream_t stream)
{
  const float* x      = (const float*)d_in[0];
  const float* logits = (const float*)d_in[1];
  const int*   masks  = (const int*)d_in[2];
  const float* ew_in  = (const float*)d_in[3];
  const float* ew_out = (const float*)d_in[4];
  const float* eb_out = (const float*)d_in[5];
  const float* gw_in  = (const float*)d_in[6];
  const float* gw_out = (const float*)d_in[7];
  const float* gb_out = (const float*)d_in[8];
  const float* gamma  = (const float*)d_in[9];
  const float* beta   = (const float*)d_in[10];
  float* out = (float*)d_out;

  char* w = (char*)d_ws;
  size_t off = 0;
  auto alloc = [&](size_t bytes) -> void* {
    off = (off + 4095) & ~(size_t)4095;
    void* p = w + off; off += bytes; return p;
  };
  const long DF = (long)DDIM * FDIM;          // 4.19M elems
  const long BF = (long)B_TOK * FDIM;         // 8.39M elems

  float* gates    = (float*)alloc((size_t)B_TOK * NE * 4);
  float* loss     = (float*)alloc(64 * 4);
  int*   tok      = (int*)alloc((size_t)NE * B_TOK * 4);
  int*   pos      = (int*)alloc((size_t)B_TOK * NE * 4);
  int*   cnts     = (int*)alloc(2 * NE * 4);
  u16*   xb       = (u16*)alloc((size_t)BD * 2);
  float* moe_bias = (float*)alloc((size_t)BD * 4);
  float* gen_p    = (float*)alloc(8 * (size_t)BD * 4);           // 8 slices (g,ks)
  float* Eout     = (float*)alloc((size_t)NE * BD * 4);          // per-expert compact f32

  // routed chunk size adaptive to remaining ws
  const size_t per = 2 * (size_t)DF * 2 + (size_t)BF * 2 + 3 * 4096; // WinT+WoutT+Hb per expert
  int CE = 16;
  while (CE > 1 && off + (size_t)CE * per > ws_size) CE >>= 1;
  u16* WinT  = (u16*)alloc((size_t)CE * DF * 2);
  u16* WoutT = (u16*)alloc((size_t)CE * DF * 2);
  u16* Hb    = (u16*)alloc((size_t)CE * BF * 2);

  hipMemsetAsync(loss, 0, 64 * 4, stream);
  gating_kernel<<<8, 256, 0, stream>>>(logits, masks, gates, loss);
  finalize_loss<<<1, 64, 0, stream>>>(loss, out + BD);
  compact_kernel<<<NE, 256, 0, stream>>>(masks, tok, pos, cnts);
  cvt_x_kernel<<<2048, 256, 0, stream>>>(x, xb);
  bias_init_kernel<<<8192, 256, 0, stream>>>(gates, eb_out, moe_bias);

  for (int e0 = 0; e0 < NE; e0 += CE) {
    transpose_cvt<<<dim3(FDIM/64, DDIM/64, CE), 256, 0, stream>>>(
        ew_in + (long)e0 * DF, WinT, DDIM, FDIM, DF, DF);
    transpose_cvt<<<dim3(DDIM/64, FDIM/64, CE), 256, 0, stream>>>(
        ew_out + (long)e0 * DF, WoutT, FDIM, DDIM, DF, DF);
    // in-proj: [cnt_pad,1024] x [4096,1024]^T -> Hb (bf16 gelu), K=1024
    gemm128<0><<<dim3(FDIM/128, B_TOK/128, CE), 256, 0, stream>>>(
        xb, DDIM, 0L, WinT, DDIM, DF, DDIM,
        Hb, BF, nullptr, 0L, tok, cnts, e0);
    // out-proj: [cnt_pad,4096] x [1024,4096]^T -> Eout (f32, compact, full-K)
    gemm128<1><<<dim3(DDIM/128, B_TOK/128, CE), 256, 0, stream>>>(
        Hb, FDIM, BF, WoutT, FDIM, DF, FDIM,
        nullptr, 0L, Eout, BD, nullptr, cnts, e0);
  }

  // general experts: reuse WinT/WoutT/Hb scratch (CE >= 2 given ws sizing)
  transpose_cvt<<<dim3(FDIM/64, DDIM/64, NG), 256, 0, stream>>>(
      gw_in, WinT, DDIM, FDIM, DF, DF);
  transpose_cvt<<<dim3(DDIM/64, FDIM/64, NG), 256, 0, stream>>>(
      gw_out, WoutT, FDIM, DDIM, DF, DF);
  gemm128<0><<<dim3(FDIM/128, B_TOK/128, NG), 256, 0, stream>>>(
      xb, DDIM, 0L, WinT, DDIM, DF, DDIM,
      Hb, BF, nullptr, 0L, nullptr, nullptr, 0);
  // general out-proj: K-split 4 (bz = g*4+ks), klen = 1024, disjoint slice writes
  gemm128<2><<<dim3(DDIM/128, B_TOK/128, NG * 4), 256, 0, stream>>>(
      Hb, FDIM, BF, WoutT, FDIM, DF, FDIM / 4,
      nullptr, 0L, gen_p, BD, nullptr, nullptr, 0);

  combine_ln_kernel<<<B_TOK, 256, 0, stream>>>(
      x, moe_bias, Eout, gen_p, gb_out, pos, gates, gamma, beta, out);
}